// Round 6
// baseline (103.604 us; speedup 1.0000x reference)
//
#include <hip/hip_runtime.h>
#include <hip/hip_bf16.h>

typedef __attribute__((ext_vector_type(4))) float f32x4;
typedef __attribute__((ext_vector_type(8))) short bf16x8;

static constexpr int NROW = 8192;
static constexpr int DDIM = 512;
static constexpr float INV_T = 10.0f;    // 1 / temperature
static constexpr float SHIFT = 70.0f;    // fixed logsumexp shift (logit max ~60)
// exp(acc*10 - 70) = exp2(acc*14.4269504 - 100.98865)
static constexpr float E2_SC = 14.4269504089f;
static constexpr float E2_BI = -100.988652759f;

__device__ __forceinline__ void gload_lds16(const void* gsrc, void* ldst) {
  __builtin_amdgcn_global_load_lds(
      (const __attribute__((address_space(1))) unsigned int*)gsrc,
      (__attribute__((address_space(3))) unsigned int*)ldst, 16, 0, 0);
}

// ---------- prep: normalize anchor rows, cast both operands to bf16 ----------
__global__ void prep_kernel(const float* __restrict__ f0,
                            const float* __restrict__ f1,
                            __hip_bfloat16* __restrict__ A,
                            __hip_bfloat16* __restrict__ B,
                            float* __restrict__ wsS) {
  int gid  = blockIdx.x * blockDim.x + threadIdx.x;
  if (gid <= NROW) wsS[gid] = 0.f;            // zero accumulators (incl. pos slot)
  int wid  = gid >> 6;                         // one wave per row
  int lane = threadIdx.x & 63;
  const float4* s0 = (const float4*)(f0 + (size_t)wid * (2 * DDIM));  // features[:,0,:]
  const float4* s1 = (const float4*)(f1 + (size_t)wid * (2 * DDIM));  // features1[:,0,:]
  float4 v0 = s0[lane], v1 = s0[lane + 64];
  float ss = v0.x * v0.x + v0.y * v0.y + v0.z * v0.z + v0.w * v0.w +
             v1.x * v1.x + v1.y * v1.y + v1.z * v1.z + v1.w * v1.w;
#pragma unroll
  for (int m = 1; m < 64; m <<= 1) ss += __shfl_xor(ss, m);
  float rn = rsqrtf(ss);
  float4 w0 = s1[lane], w1 = s1[lane + 64];
  union { __hip_bfloat16 h[4]; ushort4 u; } c0, c1, d0, d1;
  c0.h[0] = __float2bfloat16(v0.x * rn); c0.h[1] = __float2bfloat16(v0.y * rn);
  c0.h[2] = __float2bfloat16(v0.z * rn); c0.h[3] = __float2bfloat16(v0.w * rn);
  c1.h[0] = __float2bfloat16(v1.x * rn); c1.h[1] = __float2bfloat16(v1.y * rn);
  c1.h[2] = __float2bfloat16(v1.z * rn); c1.h[3] = __float2bfloat16(v1.w * rn);
  d0.h[0] = __float2bfloat16(w0.x); d0.h[1] = __float2bfloat16(w0.y);
  d0.h[2] = __float2bfloat16(w0.z); d0.h[3] = __float2bfloat16(w0.w);
  d1.h[0] = __float2bfloat16(w1.x); d1.h[1] = __float2bfloat16(w1.y);
  d1.h[2] = __float2bfloat16(w1.z); d1.h[3] = __float2bfloat16(w1.w);
  ushort4* Ao = (ushort4*)(A + (size_t)wid * DDIM);
  ushort4* Bo = (ushort4*)(B + (size_t)wid * DDIM);
  Ao[lane] = c0.u; Ao[lane + 64] = c1.u;
  Bo[lane] = d0.u; Bo[lane + 64] = d1.u;
}

// ---------- fused S = A.B^T / T with fixed-shift LSE accumulation ----------
// grid 256 = 32 row panels x 8 column splits. Block = 256 threads = 4 waves,
// M_wave = 64 rows/wave (a[4][16] A-fragments, ~256 VGPR, 1 wave/SIMD).
// Rationale: per-wave B-LDS traffic is fixed at 64 KiB/tile, so doubling rows
// per wave HALVES LDS-read cycles per FLOP (2-3k cyc/CU/tile vs MFMA 4.3k),
// turning the kernel MFMA-issue-bound instead of LDS/MFMA co-bound.
// Double-buffered B tiles; stage(t+1) issued before MFMA(t); 1 barrier/tile.
__global__ __launch_bounds__(256, 1) void sim_lse_kernel(
    const __hip_bfloat16* __restrict__ Ag,
    const __hip_bfloat16* __restrict__ Bg,
    float* __restrict__ wsS, float* __restrict__ wsPos) {
  __shared__ float4 bufA4[4096];   // 64 KiB, tiles 0,2,4,...
  __shared__ float4 bufB4[4096];   // 64 KiB, tiles 1,3,5,...

  const int tid  = threadIdx.x;
  const int w    = tid >> 6;                 // wave 0..3
  const int lane = tid & 63;
  const int g    = lane >> 4;                // k-group 0..3
  const int lr   = lane & 15;                // row-in-frag (A) / col-in-frag (B,D)

  const int p  = blockIdx.x >> 3;            // row panel 0..31
  const int cs = blockIdx.x & 7;             // column split 0..7
  const int r0 = p * 256 + w * 64;           // this wave's first row (64 rows/wave)
  const int c0 = cs * 1024;                  // first column of this split

  // staging swizzles: row n = it*4 + w, (n&7) = (it&1)*4 + w
  const int swz0 = (lane << 4) ^ (w << 4);   // even it
  const int swz1 = swz0 ^ 0x40;              // odd it

  // A fragments -> registers: a[i][ks] = A[r0+i*16+lr][ks*32 + g*8 .. +8)
  bf16x8 a[4][16];
#pragma unroll
  for (int i = 0; i < 4; i++) {
    const short* arow = (const short*)Ag + (size_t)(r0 + i * 16 + lr) * DDIM + g * 8;
#pragma unroll
    for (int ks = 0; ks < 16; ks++)
      a[i][ks] = *(const bf16x8*)(arow + ks * 32);
  }

  float sums[4][4];
#pragma unroll
  for (int i = 0; i < 4; i++)
#pragma unroll
    for (int r = 0; r < 4; r++) sums[i][r] = 0.f;
  float pos_sum = 0.f;

  f32x4 acc[4][4];

#define STAGE(BUF, T)                                                          \
  {                                                                            \
    const char* gb = (const char*)Bg + (size_t)(c0 + (T) * 64) * 1024 +        \
                     (size_t)w * 1024;                                         \
    char* lb = (char*)(BUF) + w * 1024;                                        \
    _Pragma("unroll")                                                          \
    for (int it = 0; it < 16; it++)                                            \
      gload_lds16(gb + it * 4096 + ((it & 1) ? swz1 : swz0), lb + it * 4096);  \
  }

#define MFMA_TILE(BUF)                                                         \
  {                                                                            \
    _Pragma("unroll")                                                          \
    for (int i = 0; i < 4; i++)                                                \
      _Pragma("unroll")                                                        \
      for (int j = 0; j < 4; j++) acc[i][j] = (f32x4){0.f, 0.f, 0.f, 0.f};     \
    _Pragma("unroll")                                                          \
    for (int ks = 0; ks < 16; ks++) {                                          \
      bf16x8 bf[4];                                                            \
      _Pragma("unroll")                                                        \
      for (int j = 0; j < 4; j++) {                                            \
        int n  = j * 16 + lr;                                                  \
        int kb = ks * 64 + g * 16;                                             \
        int sw = n * 1024 + (kb ^ ((n & 7) << 4));                             \
        bf[j] = *(const bf16x8*)((const char*)(BUF) + sw);                     \
      }                                                                        \
      _Pragma("unroll")                                                        \
      for (int i = 0; i < 4; i++)                                              \
        _Pragma("unroll")                                                      \
        for (int j = 0; j < 4; j++)                                            \
          acc[i][j] = __builtin_amdgcn_mfma_f32_16x16x32_bf16(a[i][ks], bf[j], \
                                                              acc[i][j], 0, 0, 0); \
    }                                                                          \
  }

#define EPILOGUE(T)                                                            \
  {                                                                            \
    const int n0e = c0 + (T) * 64;                                             \
    const bool diag_tile = (r0 < n0e + 64) && (n0e < r0 + 64);                 \
    _Pragma("unroll")                                                          \
    for (int i = 0; i < 4; i++)                                                \
      _Pragma("unroll")                                                        \
      for (int j = 0; j < 4; j++)                                              \
        _Pragma("unroll")                                                      \
        for (int r = 0; r < 4; r++) {                                          \
          float av = acc[i][j][r];                                             \
          if (diag_tile) {                                                     \
            int gr = r0 + i * 16 + g * 4 + r;                                  \
            int gc = n0e + j * 16 + lr;                                        \
            if (gr == gc) pos_sum += av * INV_T;                               \
          }                                                                    \
          sums[i][r] += exp2f(fmaf(av, E2_SC, E2_BI));                         \
        }                                                                      \
  }

  STAGE(bufA4, 0);
  __syncthreads();                            // drain: tile 0 ready

#pragma unroll 1
  for (int t = 0; t < 16; t += 2) {
    STAGE(bufB4, t + 1);                      // async; lands under MFMA below
    MFMA_TILE(bufA4);                         // tile t
    EPILOGUE(t);
    __syncthreads();                          // readers of A done; B drained (free)
    if (t + 2 < 16) STAGE(bufA4, t + 2);      // async; lands under MFMA below
    MFMA_TILE(bufB4);                         // tile t+1
    EPILOGUE(t + 1);
    __syncthreads();
  }

#undef STAGE
#undef MFMA_TILE
#undef EPILOGUE

  // reduce over the 16 lanes holding the same rows (columns partition), commit
#pragma unroll
  for (int i = 0; i < 4; i++)
#pragma unroll
    for (int r = 0; r < 4; r++) {
      float s = sums[i][r];
      s += __shfl_xor(s, 1);
      s += __shfl_xor(s, 2);
      s += __shfl_xor(s, 4);
      s += __shfl_xor(s, 8);
      if (lr == 0) atomicAdd(&wsS[r0 + i * 16 + g * 4 + r], s);
    }
  if (pos_sum != 0.f) atomicAdd(wsPos, pos_sum);
}

// ---------- finalize: loss = mean(SHIFT + log(S_r)) - mean(pos) ----------
__global__ void finalize_kernel(const float* __restrict__ wsS,
                                const float* __restrict__ wsPos,
                                float* __restrict__ out) {
  __shared__ float red[16];
  float part = 0.f;
  for (int r = threadIdx.x; r < NROW; r += 1024)
    part += SHIFT + __logf(wsS[r]);
#pragma unroll
  for (int m = 1; m < 64; m <<= 1) part += __shfl_xor(part, m);
  if ((threadIdx.x & 63) == 0) red[threadIdx.x >> 6] = part;
  __syncthreads();
  if (threadIdx.x < 16) {
    float t = red[threadIdx.x];
#pragma unroll
    for (int m = 1; m < 16; m <<= 1) t += __shfl_xor(t, m);
    if (threadIdx.x == 0) out[0] = (t - wsPos[0]) / (float)NROW;
  }
}

extern "C" void kernel_launch(void* const* d_in, const int* in_sizes, int n_in,
                              void* d_out, int out_size, void* d_ws, size_t ws_size,
                              hipStream_t stream) {
  const float* f0 = (const float*)d_in[0];
  const float* f1 = (const float*)d_in[1];
  // d_in[2] (y) is unused by the reference computation.

  __hip_bfloat16* A = (__hip_bfloat16*)d_ws;                       // 8 MiB
  __hip_bfloat16* B = A + (size_t)NROW * DDIM;                     // 8 MiB
  float* wsS  = (float*)((char*)d_ws + (size_t)2 * NROW * DDIM * 2);
  float* wsPos = wsS + NROW;

  prep_kernel<<<NROW / 4, 256, 0, stream>>>(f0, f1, A, B, wsS);
  sim_lse_kernel<<<256, 256, 0, stream>>>(A, B, wsS, wsPos);
  finalize_kernel<<<1, 1024, 0, stream>>>(wsS, wsPos, (float*)d_out);
}

// Round 7
// 80.719 us; speedup vs baseline: 1.2835x; 1.2835x over previous
//
#include <hip/hip_runtime.h>
#include <hip/hip_bf16.h>

typedef __attribute__((ext_vector_type(4))) float f32x4;

static constexpr int NROW = 8192;
static constexpr int DDIM = 512;
static constexpr float INV_T = 10.0f;    // 1 / temperature
static constexpr float SHIFT = 70.0f;    // fixed logsumexp shift (logit max ~60)
// exp(acc*10 - 70) = exp2(acc*14.4269504 - 100.98865)
static constexpr float E2_SC = 14.4269504089f;
static constexpr float E2_BI = -100.988652759f;

static constexpr int ROWB = 528;         // LDS row stride: 512 fp8 + 16 pad -> bank-uniform

// pack 4 floats into 4 fp8 e4m3 bytes (gfx950: OCP encoding)
__device__ __forceinline__ unsigned int pack_fp8x4(float x, float y, float z, float w) {
  unsigned int r = 0;
  r = __builtin_amdgcn_cvt_pk_fp8_f32(x, y, r, false);  // bytes 0,1
  r = __builtin_amdgcn_cvt_pk_fp8_f32(z, w, r, true);   // bytes 2,3
  return r;
}

// ---------- prep: normalize anchor rows, cast both operands to fp8 e4m3 ----------
__global__ void prep_kernel(const float* __restrict__ f0,
                            const float* __restrict__ f1,
                            unsigned int* __restrict__ A,   // [NROW][DDIM] fp8, as u32x128/row
                            unsigned int* __restrict__ B,
                            float* __restrict__ wsS) {
  int gid  = blockIdx.x * blockDim.x + threadIdx.x;
  if (gid <= NROW) wsS[gid] = 0.f;            // zero accumulators (incl. pos slot)
  int wid  = gid >> 6;                         // one wave per row
  int lane = threadIdx.x & 63;
  const float4* s0 = (const float4*)(f0 + (size_t)wid * (2 * DDIM));  // features[:,0,:]
  const float4* s1 = (const float4*)(f1 + (size_t)wid * (2 * DDIM));  // features1[:,0,:]
  float4 v0 = s0[lane], v1 = s0[lane + 64];
  float ss = v0.x * v0.x + v0.y * v0.y + v0.z * v0.z + v0.w * v0.w +
             v1.x * v1.x + v1.y * v1.y + v1.z * v1.z + v1.w * v1.w;
#pragma unroll
  for (int m = 1; m < 64; m <<= 1) ss += __shfl_xor(ss, m);
  float rn = rsqrtf(ss);
  float4 w0 = s1[lane], w1 = s1[lane + 64];
  A[wid * 128 + lane]      = pack_fp8x4(v0.x * rn, v0.y * rn, v0.z * rn, v0.w * rn);
  A[wid * 128 + 64 + lane] = pack_fp8x4(v1.x * rn, v1.y * rn, v1.z * rn, v1.w * rn);
  B[wid * 128 + lane]      = pack_fp8x4(w0.x, w0.y, w0.z, w0.w);
  B[wid * 128 + 64 + lane] = pack_fp8x4(w1.x, w1.y, w1.z, w1.w);
}

// ---------- fused S = A.B^T / T with fixed-shift LSE accumulation (fp8) ----------
// grid 256 = 32 row panels (BM=256: 8 waves x 32 rows) x 8 column splits.
// Round-1 schedule (measured best): sync -> stage -> sync -> MFMA+epilogue.
// fp8 halves LDS traffic: per CU per tile, LDS-read = 8 waves x 32 KiB = 3084 cyc
// < MFMA 4966 cyc -> matrix pipe is now the binding resource.
// Row stride 528 B makes ds_read_b64 (4n+8ks+2g mod 32: 64 lanes -> every bank
// exactly 4x) and the float4 stage writes bank-uniform -> no swizzle needed.
__global__ __launch_bounds__(512, 2) void sim_lse_kernel(
    const unsigned char* __restrict__ Ag,
    const unsigned char* __restrict__ Bg,
    float* __restrict__ wsS, float* __restrict__ wsPos) {
  __shared__ __align__(16) char lds[64 * ROWB];   // 33 KiB B tile [64][512] fp8, padded

  const int tid  = threadIdx.x;
  const int w    = tid >> 6;
  const int lane = tid & 63;
  const int g    = lane >> 4;                // k-group 0..3
  const int lr   = lane & 15;                // row-in-frag (A) / col-in-frag (B,D)

  const int p  = blockIdx.x >> 3;            // row panel 0..31
  const int cs = blockIdx.x & 7;             // column split 0..7
  const int r0 = p * 256 + w * 32;           // this wave's first row
  const int c0 = cs * 1024;                  // first column of this split

  // A fragments -> registers: a[i][ks] = 8 fp8 of A[r0+i*16+lr][ks*32 + g*8 .. +8)
  long a[2][16];
#pragma unroll
  for (int i = 0; i < 2; i++) {
    const char* arow = (const char*)Ag + (size_t)(r0 + i * 16 + lr) * DDIM + g * 8;
#pragma unroll
    for (int ks = 0; ks < 16; ks++)
      a[i][ks] = *(const long*)(arow + ks * 32);
  }

  float sums[2][4];
#pragma unroll
  for (int i = 0; i < 2; i++)
#pragma unroll
    for (int r = 0; r < 4; r++) sums[i][r] = 0.f;
  float pos_sum = 0.f;

  f32x4 acc[2][4];

#pragma unroll 1
  for (int t = 0; t < 16; t++) {
    const int n0 = c0 + t * 64;
    __syncthreads();                          // previous tile's readers done
    // stage: 64 rows x 512 B = 2048 16B chunks; 512 threads x 4 iters.
    // Global loads are address-only dependent -> compiler hoists them early
    // (T14 async effect); ds_writes land after the barrier.
#pragma unroll
    for (int it = 0; it < 4; it++) {
      int c = tid + it * 512;
      int n = c >> 5;
      int o = (c & 31) << 4;
      *(float4*)(lds + n * ROWB + o) =
          *(const float4*)(Bg + (size_t)(n0 + n) * DDIM + o);
    }
    __syncthreads();                          // tile ready

#pragma unroll
    for (int i = 0; i < 2; i++)
#pragma unroll
      for (int j = 0; j < 4; j++) acc[i][j] = (f32x4){0.f, 0.f, 0.f, 0.f};

#pragma unroll
    for (int ks = 0; ks < 16; ks++) {
      long bf[4];
#pragma unroll
      for (int j = 0; j < 4; j++)
        bf[j] = *(const long*)(lds + (j * 16 + lr) * ROWB + ks * 32 + g * 8);
#pragma unroll
      for (int i = 0; i < 2; i++)
#pragma unroll
        for (int j = 0; j < 4; j++)
          acc[i][j] = __builtin_amdgcn_mfma_f32_16x16x32_fp8_fp8(a[i][ks], bf[j],
                                                                 acc[i][j], 0, 0, 0);
    }

    // epilogue: capture diagonal, accumulate exp2(acc*SC + BI)
    const bool diag_tile = (r0 < n0 + 64) && (n0 < r0 + 32);
#pragma unroll
    for (int i = 0; i < 2; i++)
#pragma unroll
      for (int j = 0; j < 4; j++)
#pragma unroll
        for (int r = 0; r < 4; r++) {
          float av = acc[i][j][r];
          if (diag_tile) {
            int gr = r0 + i * 16 + g * 4 + r;  // D row = global S row
            int gc = n0 + j * 16 + lr;         // D col = global S col
            if (gr == gc) pos_sum += av * INV_T;
          }
          sums[i][r] += exp2f(fmaf(av, E2_SC, E2_BI));
        }
  }

  // reduce over the 16 lanes holding the same rows (columns partition), commit
#pragma unroll
  for (int i = 0; i < 2; i++)
#pragma unroll
    for (int r = 0; r < 4; r++) {
      float s = sums[i][r];
      s += __shfl_xor(s, 1);
      s += __shfl_xor(s, 2);
      s += __shfl_xor(s, 4);
      s += __shfl_xor(s, 8);
      if (lr == 0) atomicAdd(&wsS[r0 + i * 16 + g * 4 + r], s);
    }
  if (pos_sum != 0.f) atomicAdd(wsPos, pos_sum);
}

// ---------- finalize: loss = mean(SHIFT + log(S_r)) - mean(pos) ----------
__global__ void finalize_kernel(const float* __restrict__ wsS,
                                const float* __restrict__ wsPos,
                                float* __restrict__ out) {
  __shared__ float red[16];
  float part = 0.f;
  for (int r = threadIdx.x; r < NROW; r += 1024)
    part += SHIFT + __logf(wsS[r]);
#pragma unroll
  for (int m = 1; m < 64; m <<= 1) part += __shfl_xor(part, m);
  if ((threadIdx.x & 63) == 0) red[threadIdx.x >> 6] = part;
  __syncthreads();
  if (threadIdx.x < 16) {
    float t = red[threadIdx.x];
#pragma unroll
    for (int m = 1; m < 16; m <<= 1) t += __shfl_xor(t, m);
    if (threadIdx.x == 0) out[0] = (t - wsPos[0]) / (float)NROW;
  }
}

extern "C" void kernel_launch(void* const* d_in, const int* in_sizes, int n_in,
                              void* d_out, int out_size, void* d_ws, size_t ws_size,
                              hipStream_t stream) {
  const float* f0 = (const float*)d_in[0];
  const float* f1 = (const float*)d_in[1];
  // d_in[2] (y) is unused by the reference computation.

  unsigned char* A = (unsigned char*)d_ws;                         // 4 MiB fp8
  unsigned char* B = A + (size_t)NROW * DDIM;                      // 4 MiB fp8
  float* wsS  = (float*)(B + (size_t)NROW * DDIM);
  float* wsPos = wsS + NROW;

  prep_kernel<<<NROW / 4, 256, 0, stream>>>(f0, f1, (unsigned int*)A,
                                            (unsigned int*)B, wsS);
  sim_lse_kernel<<<256, 512, 0, stream>>>(A, B, wsS, wsPos);
  finalize_kernel<<<1, 1024, 0, stream>>>(wsS, wsPos, (float*)d_out);
}

// Round 8
// 74.657 us; speedup vs baseline: 1.3877x; 1.0812x over previous
//
#include <hip/hip_runtime.h>
#include <hip/hip_bf16.h>

typedef __attribute__((ext_vector_type(4))) float f32x4;

static constexpr int NROW = 8192;
static constexpr int DDIM = 512;
static constexpr float INV_T = 10.0f;    // 1 / temperature
static constexpr float SHIFT = 70.0f;    // fixed logsumexp shift (logit max ~60)
// exp(acc*10 - 70) = exp2(acc*14.4269504 - 100.98865)
static constexpr float E2_SC = 14.4269504089f;
static constexpr float E2_BI = -100.988652759f;

__device__ __forceinline__ void gload_lds16(const void* gsrc, void* ldst) {
  __builtin_amdgcn_global_load_lds(
      (const __attribute__((address_space(1))) unsigned int*)gsrc,
      (__attribute__((address_space(3))) unsigned int*)ldst, 16, 0, 0);
}

// pack 4 floats into 4 fp8 e4m3 bytes (gfx950: OCP encoding)
__device__ __forceinline__ unsigned int pack_fp8x4(float x, float y, float z, float w) {
  unsigned int r = 0;
  r = __builtin_amdgcn_cvt_pk_fp8_f32(x, y, r, false);  // bytes 0,1
  r = __builtin_amdgcn_cvt_pk_fp8_f32(z, w, r, true);   // bytes 2,3
  return r;
}

// ---------- prep: normalize anchor rows, cast both operands to fp8 e4m3 ----------
__global__ void prep_kernel(const float* __restrict__ f0,
                            const float* __restrict__ f1,
                            unsigned int* __restrict__ A,   // [NROW][DDIM] fp8, as u32x128/row
                            unsigned int* __restrict__ B,
                            float* __restrict__ wsS) {
  int gid  = blockIdx.x * blockDim.x + threadIdx.x;
  if (gid <= NROW) wsS[gid] = 0.f;            // zero accumulators (incl. pos slot)
  int wid  = gid >> 6;                         // one wave per row
  int lane = threadIdx.x & 63;
  const float4* s0 = (const float4*)(f0 + (size_t)wid * (2 * DDIM));  // features[:,0,:]
  const float4* s1 = (const float4*)(f1 + (size_t)wid * (2 * DDIM));  // features1[:,0,:]
  float4 v0 = s0[lane], v1 = s0[lane + 64];
  float ss = v0.x * v0.x + v0.y * v0.y + v0.z * v0.z + v0.w * v0.w +
             v1.x * v1.x + v1.y * v1.y + v1.z * v1.z + v1.w * v1.w;
#pragma unroll
  for (int m = 1; m < 64; m <<= 1) ss += __shfl_xor(ss, m);
  float rn = rsqrtf(ss);
  float4 w0 = s1[lane], w1 = s1[lane + 64];
  A[wid * 128 + lane]      = pack_fp8x4(v0.x * rn, v0.y * rn, v0.z * rn, v0.w * rn);
  A[wid * 128 + 64 + lane] = pack_fp8x4(v1.x * rn, v1.y * rn, v1.z * rn, v1.w * rn);
  B[wid * 128 + lane]      = pack_fp8x4(w0.x, w0.y, w0.z, w0.w);
  B[wid * 128 + 64 + lane] = pack_fp8x4(w1.x, w1.y, w1.z, w1.w);
}

// ---------- fused S = A.B^T / T with fixed-shift LSE accumulation (fp8) ----------
// grid 256 = 32 row panels (BM=256: 8 waves x 32 rows) x 8 column splits.
// Double-buffered 2x32 KiB fp8 B tiles staged via global_load_lds (linear LDS
// dest, XOR swizzle ((n&7)<<4) applied to the GLOBAL source address; read side
// applies the same XOR -> 64 lanes hit all 32 banks 2-way = conflict-free).
// fp8 gives the LDS pipe slack (read 256KB + write 32KB ~ 3.4k cyc < MFMA
// 4.97k cyc per tile per CU), so stage(t+1) hides fully under MFMA(t) and the
// single barrier's vmcnt(0) drain is free. This is why dbuf failed at bf16
// (LDS pipe saturated) but should pay now.
__global__ __launch_bounds__(512, 2) void sim_lse_kernel(
    const unsigned char* __restrict__ Ag,
    const unsigned char* __restrict__ Bg,
    float* __restrict__ wsS, float* __restrict__ wsPos) {
  __shared__ __align__(16) char bufA[64 * 512];   // 32 KiB, tiles 0,2,4,...
  __shared__ __align__(16) char bufB[64 * 512];   // 32 KiB, tiles 1,3,5,...

  const int tid  = threadIdx.x;
  const int w    = tid >> 6;
  const int lane = tid & 63;
  const int g    = lane >> 4;                // k-group 0..3
  const int lr   = lane & 15;                // row-in-frag (A) / col-in-frag (B,D)

  const int p  = blockIdx.x >> 3;            // row panel 0..31
  const int cs = blockIdx.x & 7;             // column split 0..7
  const int r0 = p * 256 + w * 32;           // this wave's first row
  const int c0 = cs * 1024;                  // first column of this split

  // staging: wave w stages row-pairs pr = it*8+w (it=0..3); lane covers 16 B of
  // row n = 2*pr + (lane>>5); source byte = ((lane&31)<<4) ^ ((n&7)<<4), and
  // (n&7) = (2w + (lane>>5)) & 7 -> per-thread constant swizzle.
  const int hi      = lane >> 5;
  const int stg_off = ((lane & 31) << 4) ^ (((2 * w + hi) & 7) << 4);
  const int stg_row = hi;                    // row parity within the pair

  // A fragments -> registers: a[i][ks] = 8 fp8 of A[r0+i*16+lr][ks*32 + g*8 .. +8)
  long a[2][16];
#pragma unroll
  for (int i = 0; i < 2; i++) {
    const char* arow = (const char*)Ag + (size_t)(r0 + i * 16 + lr) * DDIM + g * 8;
#pragma unroll
    for (int ks = 0; ks < 16; ks++)
      a[i][ks] = *(const long*)(arow + ks * 32);
  }

  float sums[2][4];
#pragma unroll
  for (int i = 0; i < 2; i++)
#pragma unroll
    for (int r = 0; r < 4; r++) sums[i][r] = 0.f;
  float pos_sum = 0.f;

  f32x4 acc[2][4];

#define STAGE(BUF, T)                                                          \
  {                                                                            \
    const char* gb = (const char*)Bg + (size_t)(c0 + (T) * 64) * DDIM;         \
    _Pragma("unroll")                                                          \
    for (int it = 0; it < 4; it++) {                                           \
      int pr = it * 8 + w;                                                     \
      gload_lds16(gb + (size_t)(2 * pr + stg_row) * DDIM + stg_off,            \
                  (char*)(BUF) + pr * 1024);                                   \
    }                                                                          \
  }

#define MFMA_TILE(BUF)                                                         \
  {                                                                            \
    _Pragma("unroll")                                                          \
    for (int i = 0; i < 2; i++)                                                \
      _Pragma("unroll")                                                        \
      for (int j = 0; j < 4; j++) acc[i][j] = (f32x4){0.f, 0.f, 0.f, 0.f};     \
    _Pragma("unroll")                                                          \
    for (int ks = 0; ks < 16; ks++) {                                          \
      long bf[4];                                                              \
      _Pragma("unroll")                                                        \
      for (int j = 0; j < 4; j++) {                                            \
        int n = j * 16 + lr;                                                   \
        bf[j] = *(const long*)((const char*)(BUF) +                            \
                               ((n * 512 + ks * 32 + g * 8) ^ ((n & 7) << 4)));\
      }                                                                        \
      _Pragma("unroll")                                                        \
      for (int i = 0; i < 2; i++)                                              \
        _Pragma("unroll")                                                      \
        for (int j = 0; j < 4; j++)                                            \
          acc[i][j] = __builtin_amdgcn_mfma_f32_16x16x32_fp8_fp8(              \
              a[i][ks], bf[j], acc[i][j], 0, 0, 0);                            \
    }                                                                          \
  }

#define EPILOGUE(T)                                                            \
  {                                                                            \
    const int n0e = c0 + (T) * 64;                                             \
    const bool diag_tile = (r0 < n0e + 64) && (n0e < r0 + 32);                 \
    _Pragma("unroll")                                                          \
    for (int i = 0; i < 2; i++)                                                \
      _Pragma("unroll")                                                        \
      for (int j = 0; j < 4; j++)                                              \
        _Pragma("unroll")                                                      \
        for (int r = 0; r < 4; r++) {                                          \
          float av = acc[i][j][r];                                             \
          if (diag_tile) {                                                     \
            int gr = r0 + i * 16 + g * 4 + r;                                  \
            int gc = n0e + j * 16 + lr;                                        \
            if (gr == gc) pos_sum += av * INV_T;                               \
          }                                                                    \
          sums[i][r] += exp2f(fmaf(av, E2_SC, E2_BI));                         \
        }                                                                      \
  }

  STAGE(bufA, 0);
  __syncthreads();                            // drain: tile 0 ready

#pragma unroll 1
  for (int t = 0; t < 16; t += 2) {
    STAGE(bufB, t + 1);                       // async; lands under MFMA below
    MFMA_TILE(bufA);                          // tile t
    EPILOGUE(t);
    __syncthreads();                          // readers of A done; B drained (free)
    if (t + 2 < 16) STAGE(bufA, t + 2);       // async; lands under MFMA below
    MFMA_TILE(bufB);                          // tile t+1
    EPILOGUE(t + 1);
    __syncthreads();
  }

#undef STAGE
#undef MFMA_TILE
#undef EPILOGUE

  // reduce over the 16 lanes holding the same rows (columns partition), commit
#pragma unroll
  for (int i = 0; i < 2; i++)
#pragma unroll
    for (int r = 0; r < 4; r++) {
      float s = sums[i][r];
      s += __shfl_xor(s, 1);
      s += __shfl_xor(s, 2);
      s += __shfl_xor(s, 4);
      s += __shfl_xor(s, 8);
      if (lr == 0) atomicAdd(&wsS[r0 + i * 16 + g * 4 + r], s);
    }
  if (pos_sum != 0.f) atomicAdd(wsPos, pos_sum);
}

// ---------- finalize: loss = mean(SHIFT + log(S_r)) - mean(pos) ----------
__global__ void finalize_kernel(const float* __restrict__ wsS,
                                const float* __restrict__ wsPos,
                                float* __restrict__ out) {
  __shared__ float red[16];
  float part = 0.f;
  for (int r = threadIdx.x; r < NROW; r += 1024)
    part += SHIFT + __logf(wsS[r]);
#pragma unroll
  for (int m = 1; m < 64; m <<= 1) part += __shfl_xor(part, m);
  if ((threadIdx.x & 63) == 0) red[threadIdx.x >> 6] = part;
  __syncthreads();
  if (threadIdx.x < 16) {
    float t = red[threadIdx.x];
#pragma unroll
    for (int m = 1; m < 16; m <<= 1) t += __shfl_xor(t, m);
    if (threadIdx.x == 0) out[0] = (t - wsPos[0]) / (float)NROW;
  }
}

extern "C" void kernel_launch(void* const* d_in, const int* in_sizes, int n_in,
                              void* d_out, int out_size, void* d_ws, size_t ws_size,
                              hipStream_t stream) {
  const float* f0 = (const float*)d_in[0];
  const float* f1 = (const float*)d_in[1];
  // d_in[2] (y) is unused by the reference computation.

  unsigned char* A = (unsigned char*)d_ws;                         // 4 MiB fp8
  unsigned char* B = A + (size_t)NROW * DDIM;                      // 4 MiB fp8
  float* wsS  = (float*)(B + (size_t)NROW * DDIM);
  float* wsPos = wsS + NROW;

  prep_kernel<<<NROW / 4, 256, 0, stream>>>(f0, f1, (unsigned int*)A,
                                            (unsigned int*)B, wsS);
  sim_lse_kernel<<<256, 512, 0, stream>>>(A, B, wsS, wsPos);
  finalize_kernel<<<1, 1024, 0, stream>>>(wsS, wsPos, (float*)d_out);
}